// Round 7
// baseline (298.164 us; speedup 1.0000x reference)
//
#include <hip/hip_runtime.h>

#define XS     256
#define XS2    65536
#define LAT    10
#define BR     8             // rows per bin group
#define NG     (XS / BR)     // 32 groups per image
#define NBINS  512           // B(16) * NG(32)
#define P1     2048          // blocks for place pass
#define K_MAX  16            // max items per thread in place
#define CAP    3200          // per-block record region (>= IPB)
#define TAB    513           // per-block table entries (512 offsets + total)
#define CELLW  128           // 2x2 cells: 128 column-pairs
#define QS     256.0f        // fixed-point scale 2^8 (range +-128 per field)

// Native no-return f32 global atomic (global_atomic_add_f32).
__device__ __forceinline__ void fadd_atomic(float* p, float v) {
    unsafeAtomicAdd(p, v);
}

__device__ __forceinline__ void lds_add_u64(unsigned long long* p,
                                            unsigned long long v) {
    __hip_atomic_fetch_add(p, v, __ATOMIC_RELAXED, __HIP_MEMORY_SCOPE_WORKGROUP);
}

// pack 4 signed 16-bit fixed-point fields into a u64 (carry-exact under add
// as long as every partial field-sum stays within +-2^15).
__device__ __forceinline__ unsigned long long pack4(int q0, int q1, int q2, int q3) {
    return (unsigned long long)((long long)q0 + ((long long)q1 << 16) +
                                ((long long)q2 << 32) + ((long long)q3 << 48));
}

// ---------------------------------------------------------------------------
// Coordinate math (fmaf-pinned; shared by all paths).
// ---------------------------------------------------------------------------
__device__ __forceinline__ void compute_rc(const float* __restrict__ flow,
                                           const int* __restrict__ inds,
                                           const float* __restrict__ rot,
                                           const float* __restrict__ shifts,
                                           int b, int n, int N,
                                           int& r, int& c, float& f0, float& f1) {
    const float* R = rot + b * 9;
    float r00 = R[0], r01 = R[1], r02 = R[2];
    float r10 = R[3], r11 = R[4], r12 = R[5];
    float s0 = shifts[b * 2 + 0], s1 = shifts[b * 2 + 1];
    size_t fo = ((size_t)b * N + n) * 3;
    float fw0 = flow[fo + 0], fw1 = flow[fo + 1], fw2 = flow[fo + 2];
    float v0 = (float)inds[n * 3 + 2] - 128.0f + fw0;
    float v1 = (float)inds[n * 3 + 1] - 128.0f + fw1;
    float v2 = (float)inds[n * 3 + 0] - 128.0f + fw2;
    float p0 = fmaf(v0, r00, fmaf(v1, r01, fmaf(v2, r02, 128.0f - s0)));
    float p1 = fmaf(v0, r10, fmaf(v1, r11, fmaf(v2, r12, 128.0f - s1)));
    float cs0 = p1, cs1 = p0;     // c_sampling = (coords[...,1], coords[...,0])
    float ff0 = floorf(cs0), ff1 = floorf(cs1);
    r = (int)ff0; c = (int)ff1;
    f0 = cs0 - ff0; f1 = cs1 - ff1;
}

// JAX .at[].add semantics: negative indices wrap once, then OOB dropped.
__device__ __forceinline__ void corner_atomic(float* I, int rr, int cc, float a) {
    if (rr >= -XS && rr < XS && cc >= -XS && cc < XS)
        fadd_atomic(I + ((rr + XS) & (XS - 1)) * XS + ((cc + XS) & (XS - 1)), a);
}

// fast path iff rows r, r+1 both valid and don't wrap-split.
__device__ __forceinline__ bool is_fast(int r) {
    return (r >= -XS) && (r <= XS - 2) && (r != -1);
}

// ---------------------------------------------------------------------------
// Pass 1: fused bin+place, per-block regions, ZERO global atomics.
// Record: low = rig[0:2] wc[3:10] cv0[11] cv1[12] q0[13:21] q1[22:30];
// high = amp f32 bits.
// ---------------------------------------------------------------------------
__global__ void __launch_bounds__(256)
place_kernel(const float* __restrict__ flow,
             const float* __restrict__ values,
             const int* __restrict__ inds,
             const float* __restrict__ rot,
             const float* __restrict__ shifts,
             unsigned* __restrict__ tab,
             unsigned long long* __restrict__ recs,
             float* __restrict__ img,
             int N, int TI, int IPB) {
    __shared__ unsigned lcnt[NBINS];
    __shared__ unsigned lscan[NBINS];
    __shared__ unsigned sh[256];
    int t = threadIdx.x;
    lcnt[t] = 0; lcnt[t + 256] = 0;
    __syncthreads();

    unsigned long long rec[K_MAX];
    unsigned meta[K_MAX];        // bin | rank<<9 ; 0xFFFFFFFF = none
    int s = blockIdx.x * IPB;
    int e = min(s + IPB, TI);

#pragma unroll
    for (int k = 0; k < K_MAX; k++) {
        meta[k] = 0xFFFFFFFFu;
        int i = s + t + k * 256;
        if (i < e) {
            int b = i / N, n = i - b * N;
            int r, c; float f0, f1;
            compute_rc(flow, inds, rot, shifts, b, n, N, r, c, f0, f1);
            float amp = values[n];
            if (is_fast(r)) {
                int wr = (r + XS) & (XS - 1);
                int wc = c & (XS - 1);
                unsigned cv0 = (c >= -XS && c < XS) ? 1u : 0u;
                unsigned cv1 = (c + 1 >= -XS && c + 1 < XS) ? 1u : 0u;
                unsigned q0 = min(511u, (unsigned)(f0 * 512.0f + 0.5f));
                unsigned q1 = min(511u, (unsigned)(f1 * 512.0f + 0.5f));
                unsigned word = (unsigned)(wr & 7) | ((unsigned)wc << 3) |
                                (cv0 << 11) | (cv1 << 12) | (q0 << 13) | (q1 << 22);
                int bin = b * NG + (wr >> 3);
                unsigned rank = atomicAdd(&lcnt[bin], 1u);
                meta[k] = (unsigned)bin | (rank << 9);
                rec[k] = ((unsigned long long)__float_as_uint(amp) << 32) | word;
            } else {
                float g0 = 1.0f - f0, g1 = 1.0f - f1;
                float* I = img + (size_t)b * XS2;
                corner_atomic(I, r,     c,     amp * g0 * g1);
                corner_atomic(I, r + 1, c,     amp * f0 * g1);
                corner_atomic(I, r + 1, c + 1, amp * f0 * f1);
                corner_atomic(I, r,     c + 1, amp * g0 * f1);
            }
        }
    }
    __syncthreads();

    // exclusive scan of lcnt[512] -> lscan (thread t owns pair 2t, 2t+1)
    unsigned v0 = lcnt[2 * t], v1 = lcnt[2 * t + 1];
    unsigned psum = v0 + v1;
    sh[t] = psum; __syncthreads();
    for (int st = 1; st < 256; st <<= 1) {
        unsigned add = (t >= st) ? sh[t - st] : 0u;
        __syncthreads();
        sh[t] += add;
        __syncthreads();
    }
    unsigned run = sh[t] - psum;
    lscan[2 * t] = run;
    lscan[2 * t + 1] = run + v0;
    __syncthreads();

    // publish table (offsets + total), write records to own region
    unsigned* tb = tab + (size_t)blockIdx.x * TAB;
    tb[t] = lscan[t];
    tb[t + 256] = lscan[t + 256];
    if (t == 0) tb[512] = sh[255];

    unsigned long long* rb = recs + (size_t)blockIdx.x * CAP;
#pragma unroll
    for (int k = 0; k < K_MAX; k++) {
        unsigned m = meta[k];
        if (m != 0xFFFFFFFFu) {
            unsigned bin = m & (NBINS - 1);
            rb[lscan[bin] + (m >> 9)] = rec[k];
        }
    }
}

// ---------------------------------------------------------------------------
// Pass 2: 2x2-pixel u64 cells, 4x16-bit fixed point (step 2^-8, range +-128).
// Fields: q0=(r0,c0) q1=(r1,c0) q2=(r0,c1) q3=(r1,c1). Avg 1.5 atomics/rec.
// Blocks: (bin, sp) with sp interleaving place blocks by parity.
// ---------------------------------------------------------------------------
__global__ void __launch_bounds__(256)
accum_kernel(const unsigned long long* __restrict__ recs,
             const unsigned* __restrict__ tab,
             float* __restrict__ reps,
             float* __restrict__ aprons, int B) {
    int bin = blockIdx.x >> 1, sp = blockIdx.x & 1;
    int b = bin >> 5, g = bin & 31;
    __shared__ unsigned long long tile[BR * CELLW];   // 8 KB
    int t = threadIdx.x;
    for (int k = t; k < BR * CELLW; k += 256) tile[k] = 0ull;
    __syncthreads();

#pragma unroll
    for (int q = 0; q < P1 / 512; q++) {          // 4 blocks per thread
        int blk = sp + 2 * (q * 256 + t);
        const unsigned* tb = tab + (size_t)blk * TAB + bin;
        unsigned o = tb[0], e2 = tb[1];           // adjacent -> one dwordx2
        const unsigned long long* rb = recs + (size_t)blk * CAP;
        for (unsigned i = o; i < e2; i++) {
            unsigned long long rc = rb[i];
            unsigned w = (unsigned)rc;
            float amp = __uint_as_float((unsigned)(rc >> 32));
            int rig = w & 7, wc = (w >> 3) & 255;
            float f0 = (float)((w >> 13) & 511) * (1.0f / 512.0f);
            float f1 = (float)((w >> 22) & 511) * (1.0f / 512.0f);
            float g0 = 1.0f - f0, g1 = 1.0f - f1;
            bool cv0 = (w >> 11) & 1, cv1 = (w >> 12) & 1;
            int base = rig * CELLW;
            int i00 = __float2int_rn(amp * g0 * g1 * QS);  // (r, wc)
            int i10 = __float2int_rn(amp * f0 * g1 * QS);  // (r+1, wc)
            int i01 = __float2int_rn(amp * g0 * f1 * QS);  // (r, wc+1)
            int i11 = __float2int_rn(amp * f0 * f1 * QS);  // (r+1, wc+1)
            if ((wc & 1) == 0) {
                unsigned long long inc = pack4(cv0 ? i00 : 0, cv0 ? i10 : 0,
                                               cv1 ? i01 : 0, cv1 ? i11 : 0);
                if (inc) lds_add_u64(&tile[base + (wc >> 1)], inc);
            } else {
                if (cv0) lds_add_u64(&tile[base + (wc >> 1)], pack4(0, 0, i00, i10));
                if (cv1) lds_add_u64(&tile[base + (((wc + 1) & 255) >> 1)],
                                     pack4(i01, i11, 0, 0));
            }
        }
    }
    __syncthreads();

    // flush: thread t = column; carry row1-part downward; row 8 -> apron.
    int c = t, j = c >> 1, p = c & 1;
    const float invS = 1.0f / QS;
    float* rep = reps + ((size_t)sp * B + b) * XS2;
    float carry = 0.0f;
#pragma unroll
    for (int rig = 0; rig < BR; rig++) {
        long long s = (long long)tile[rig * CELLW + j];
        int q0 = (int)(short)(s & 0xffff); s = (s - q0) >> 16;
        int q1 = (int)(short)(s & 0xffff); s = (s - q1) >> 16;
        int q2 = (int)(short)(s & 0xffff); s = (s - q2) >> 16;
        int q3 = (int)s;
        float r0 = p ? (float)q2 : (float)q0;
        float r1 = p ? (float)q3 : (float)q1;
        rep[(g * BR + rig) * XS + c] = (carry + r0) * invS;
        carry = r1;
    }
    aprons[((size_t)bin * 2 + sp) * XS + c] = carry * invS;
}

// ---------------------------------------------------------------------------
// Fallback direct-scatter (tiny ws / unexpected shapes).
// ---------------------------------------------------------------------------
__global__ void scatter_kernel(const float* __restrict__ flow,
                               const float* __restrict__ values,
                               const int* __restrict__ inds,
                               const float* __restrict__ rot,
                               const float* __restrict__ shifts,
                               float* __restrict__ img, int N) {
    int b = blockIdx.y;
    int n = blockIdx.x * blockDim.x + threadIdx.x;
    if (n >= N) return;
    int r, c; float f0, f1;
    compute_rc(flow, inds, rot, shifts, b, n, N, r, c, f0, f1);
    float amp = values[n];
    float g0 = 1.0f - f0, g1 = 1.0f - f1;
    float* I = img + (size_t)b * XS2;
    corner_atomic(I, r,     c,     amp * g0 * g1);
    corner_atomic(I, r + 1, c,     amp * f0 * g1);
    corner_atomic(I, r + 1, c + 1, amp * f0 * f1);
    corner_atomic(I, r,     c + 1, amp * g0 * f1);
}

// ---------------------------------------------------------------------------
// MLP split-K partials.
// ---------------------------------------------------------------------------
__global__ void mlp_partial(const float* __restrict__ x,
                            const float* __restrict__ w1,
                            float* __restrict__ hraw, int B) {
    int base = blockIdx.x * 256;
    int t = threadIdx.x;
    if (t >= B * LAT) return;
    int b = t / LAT, l = t - b * LAT;
    const float* xb = x + (size_t)b * XS2 + base;
    const float* w  = w1 + (size_t)base * LAT + l;
    float acc = 0.0f;
#pragma unroll 8
    for (int e = 0; e < 256; e++) acc += xb[e] * w[e * LAT];
    fadd_atomic(&hraw[b * LAT + l], acc);
}

// ---------------------------------------------------------------------------
// Fused combine + separable 3x3 blur + per-batch affine.
// S[row] = img + rep0 + rep1 (+ aprons at row = 8k, k>=1). fastpath=0 skips reps.
// ---------------------------------------------------------------------------
__device__ __forceinline__ float S_load(const float* __restrict__ img,
                                        const float* __restrict__ reps,
                                        const float* __restrict__ aprons,
                                        int B, int b, int row, int c, int fast) {
    size_t o = (size_t)b * XS2 + row * XS + c;
    float v = img[o];
    if (fast) {
        v += reps[o] + reps[(size_t)B * XS2 + o];
        if (row > 0 && (row & 7) == 0) {
            size_t bin = (size_t)b * NG + ((row >> 3) - 1);
            v += aprons[bin * 2 * XS + c] + aprons[(bin * 2 + 1) * XS + c];
        }
    }
    return v;
}

__global__ void blur_kernel(const float* __restrict__ img,
                            const float* __restrict__ reps,
                            const float* __restrict__ aprons,
                            const float* __restrict__ hraw,
                            const float* __restrict__ b1,
                            const float* __restrict__ w2,
                            const float* __restrict__ b2,
                            float* __restrict__ out, int B, int fast) {
    int b = blockIdx.y, r = blockIdx.x, c = threadIdx.x;
    float av = b2[0], bv = b2[1];
#pragma unroll
    for (int l = 0; l < LAT; l++) {
        float h = hraw[b * LAT + l] + b1[l];
        h = h > 0.0f ? h : 0.0f;
        av += h * w2[l * 2 + 0];
        bv += h * w2[l * 2 + 1];
    }
    const float g   = 0.6065306597126334f;   // exp(-0.5)
    const float inv = 1.0f / (1.0f + 2.0f * g);
    float up  = (r > 0)      ? S_load(img, reps, aprons, B, b, r - 1, c, fast) : 0.0f;
    float mid =                S_load(img, reps, aprons, B, b, r,     c, fast);
    float dn  = (r < XS - 1) ? S_load(img, reps, aprons, B, b, r + 1, c, fast) : 0.0f;
    float v = (g * (up + dn) + mid) * inv;
    __shared__ float row[XS + 2];
    row[c + 1] = v;
    if (c == 0) { row[0] = 0.0f; row[XS + 1] = 0.0f; }
    __syncthreads();
    float hh = (g * (row[c] + row[c + 2]) + v) * inv;
    out[(size_t)b * XS2 + (size_t)r * XS + c] = av * hh + bv;
}

extern "C" void kernel_launch(void* const* d_in, const int* in_sizes, int n_in,
                              void* d_out, int out_size, void* d_ws, size_t ws_size,
                              hipStream_t stream) {
    const float* flow   = (const float*)d_in[0];
    const float* x      = (const float*)d_in[1];
    const float* values = (const float*)d_in[2];
    const float* rot    = (const float*)d_in[3];
    const float* shifts = (const float*)d_in[4];
    const float* w1     = (const float*)d_in[5];
    const float* b1     = (const float*)d_in[6];
    const float* w2     = (const float*)d_in[7];
    const float* b2     = (const float*)d_in[8];
    const int*   inds   = (const int*)d_in[9];

    int N = in_sizes[2];          // values: (N,)
    int B = in_sizes[4] / 2;      // shifts: (B,2)
    int TI  = B * N;
    int IPB = (TI + P1 - 1) / P1;

    // workspace layout (all chunk sizes are multiples of 8B)
    size_t imgElems = (size_t)B * XS2;
    float*    img   = (float*)d_ws;
    float*    hraw  = img + imgElems;                     // 256 floats reserved
    unsigned long long* recs = (unsigned long long*)(hraw + 256);   // P1*CAP
    unsigned* tabp  = (unsigned*)(recs + (size_t)P1 * CAP);         // P1*TAB (+pad)
    float*    reps  = (float*)(tabp + (size_t)P1 * TAB + 2);        // 2*B*XS2
    float*    aprons = reps + 2 * imgElems;               // NBINS*2*XS
    size_t needed = (size_t)((char*)(aprons + (size_t)NBINS * 2 * XS) - (char*)d_ws);

    bool fast = (B * NG == NBINS) && (ws_size >= needed) &&
                (IPB <= CAP) && (IPB <= K_MAX * 256);

    hipMemsetAsync(d_ws, 0, (imgElems + 256) * sizeof(float), stream);

    if (fast) {
        place_kernel<<<P1, 256, 0, stream>>>(flow, values, inds, rot, shifts,
                                             tabp, recs, img, N, TI, IPB);
        accum_kernel<<<NBINS * 2, 256, 0, stream>>>(recs, tabp, reps, aprons, B);
    } else {
        dim3 g1((N + 255) / 256, B);
        scatter_kernel<<<g1, 256, 0, stream>>>(flow, values, inds, rot, shifts, img, N);
    }

    mlp_partial<<<XS2 / 256, 256, 0, stream>>>(x, w1, hraw, B);

    dim3 g3(XS, B);
    blur_kernel<<<g3, XS, 0, stream>>>(img, reps, aprons, hraw, b1, w2, b2,
                                       (float*)d_out, B, fast ? 1 : 0);
}

// Round 8
// 221.109 us; speedup vs baseline: 1.3485x; 1.3485x over previous
//
#include <hip/hip_runtime.h>

#define XS     256
#define XS2    65536
#define LAT    10
#define BR     8             // rows per bin group
#define NG     (XS / BR)     // 32 groups per image
#define NBINS  512           // B(16) * NG(32)
#define P1     1024          // blocks for place pass
#define K_MAX  25            // max items per thread in place (IPB<=6400)
#define BINCAP 15360         // per-bin record capacity (mean ~12.4k)
#define SPLIT  2             // accum sub-blocks per bin
#define CELLW  128           // 2x2 cells: 128 column-pairs
#define QS     256.0f        // fixed-point scale 2^8 (field range +-128)

// Native no-return f32 global atomic (global_atomic_add_f32).
__device__ __forceinline__ void fadd_atomic(float* p, float v) {
    unsafeAtomicAdd(p, v);
}

__device__ __forceinline__ void lds_add_u64(unsigned long long* p,
                                            unsigned long long v) {
    __hip_atomic_fetch_add(p, v, __ATOMIC_RELAXED, __HIP_MEMORY_SCOPE_WORKGROUP);
}

// pack 4 signed 16-bit fixed-point fields into a u64 (carry-exact under add
// while every partial field-sum stays within +-2^15).
__device__ __forceinline__ unsigned long long pack4(int q0, int q1, int q2, int q3) {
    return (unsigned long long)((long long)q0 + ((long long)q1 << 16) +
                                ((long long)q2 << 32) + ((long long)q3 << 48));
}

// ---------------------------------------------------------------------------
// Coordinate math (fmaf-pinned; shared by all paths).
// ---------------------------------------------------------------------------
__device__ __forceinline__ void compute_rc(const float* __restrict__ flow,
                                           const int* __restrict__ inds,
                                           const float* __restrict__ rot,
                                           const float* __restrict__ shifts,
                                           int b, int n, int N,
                                           int& r, int& c, float& f0, float& f1) {
    const float* R = rot + b * 9;
    float r00 = R[0], r01 = R[1], r02 = R[2];
    float r10 = R[3], r11 = R[4], r12 = R[5];
    float s0 = shifts[b * 2 + 0], s1 = shifts[b * 2 + 1];
    size_t fo = ((size_t)b * N + n) * 3;
    float fw0 = flow[fo + 0], fw1 = flow[fo + 1], fw2 = flow[fo + 2];
    float v0 = (float)inds[n * 3 + 2] - 128.0f + fw0;
    float v1 = (float)inds[n * 3 + 1] - 128.0f + fw1;
    float v2 = (float)inds[n * 3 + 0] - 128.0f + fw2;
    float p0 = fmaf(v0, r00, fmaf(v1, r01, fmaf(v2, r02, 128.0f - s0)));
    float p1 = fmaf(v0, r10, fmaf(v1, r11, fmaf(v2, r12, 128.0f - s1)));
    float cs0 = p1, cs1 = p0;     // c_sampling = (coords[...,1], coords[...,0])
    float ff0 = floorf(cs0), ff1 = floorf(cs1);
    r = (int)ff0; c = (int)ff1;
    f0 = cs0 - ff0; f1 = cs1 - ff1;
}

// JAX .at[].add semantics: negative indices wrap once, then OOB dropped.
__device__ __forceinline__ void corner_atomic(float* I, int rr, int cc, float a) {
    if (rr >= -XS && rr < XS && cc >= -XS && cc < XS)
        fadd_atomic(I + ((rr + XS) & (XS - 1)) * XS + ((cc + XS) & (XS - 1)), a);
}

// fast path iff rows r, r+1 both valid and don't wrap-split.
__device__ __forceinline__ bool is_fast(int r) {
    return (r >= -XS) && (r <= XS - 2) && (r != -1);
}

// Record: low = rig[0:2] wc[3:10] cv0[11] cv1[12] q0[13:21] q1[22:30];
// high = amp f32 bits.
__device__ __forceinline__ void rec_fallback(unsigned long long rec, int bin,
                                             float* __restrict__ img) {
    unsigned w = (unsigned)rec;
    float amp = __uint_as_float((unsigned)(rec >> 32));
    int b = bin >> 5, g = bin & 31;
    int rig = w & 7, wc = (w >> 3) & 255;
    int wr = g * BR + rig;
    float f0 = (float)((w >> 13) & 511) * (1.0f / 512.0f);
    float f1 = (float)((w >> 22) & 511) * (1.0f / 512.0f);
    float g0 = 1.0f - f0, g1 = 1.0f - f1;
    float* I = img + (size_t)b * XS2;
    if (w & (1u << 11)) {
        fadd_atomic(&I[wr * XS + wc],       amp * g0 * g1);
        fadd_atomic(&I[(wr + 1) * XS + wc], amp * f0 * g1);
    }
    if (w & (1u << 12)) {
        int wc1 = (wc + 1) & 255;
        fadd_atomic(&I[wr * XS + wc1],       amp * g0 * f1);
        fadd_atomic(&I[(wr + 1) * XS + wc1], amp * f0 * f1);
    }
}

// ---------------------------------------------------------------------------
// Pass 1 (fused hist+place): LDS rtn-atomic per item gives in-block rank;
// one global cursor atomic per (bin,block) reserves bin-contiguous space.
// ---------------------------------------------------------------------------
__global__ void __launch_bounds__(256)
place_kernel(const float* __restrict__ flow,
             const float* __restrict__ values,
             const int* __restrict__ inds,
             const float* __restrict__ rot,
             const float* __restrict__ shifts,
             unsigned* __restrict__ gcursor,
             unsigned long long* __restrict__ recs,
             float* __restrict__ img,
             int N, int TI, int IPB) {
    __shared__ unsigned lcnt[NBINS];
    __shared__ unsigned lbase[NBINS];
    int t = threadIdx.x;
    lcnt[t] = 0; lcnt[t + 256] = 0;
    __syncthreads();

    unsigned long long rec[K_MAX];
    unsigned meta[K_MAX];        // bin | rank<<9 ; 0xFFFFFFFF = none
    int s = blockIdx.x * IPB;
    int e = min(s + IPB, TI);

#pragma unroll
    for (int k = 0; k < K_MAX; k++) {
        meta[k] = 0xFFFFFFFFu;
        int i = s + t + k * 256;
        if (i < e) {
            int b = i / N, n = i - b * N;
            int r, c; float f0, f1;
            compute_rc(flow, inds, rot, shifts, b, n, N, r, c, f0, f1);
            float amp = values[n];
            if (is_fast(r)) {
                int wr = (r + XS) & (XS - 1);
                int wc = c & (XS - 1);
                unsigned cv0 = (c >= -XS && c < XS) ? 1u : 0u;
                unsigned cv1 = (c + 1 >= -XS && c + 1 < XS) ? 1u : 0u;
                unsigned q0 = min(511u, (unsigned)(f0 * 512.0f + 0.5f));
                unsigned q1 = min(511u, (unsigned)(f1 * 512.0f + 0.5f));
                unsigned word = (unsigned)(wr & 7) | ((unsigned)wc << 3) |
                                (cv0 << 11) | (cv1 << 12) | (q0 << 13) | (q1 << 22);
                int bin = b * NG + (wr >> 3);
                unsigned rank = atomicAdd(&lcnt[bin], 1u);
                meta[k] = (unsigned)bin | (rank << 9);   // rank < 6400 < 2^13
                rec[k] = ((unsigned long long)__float_as_uint(amp) << 32) | word;
            } else {
                float g0 = 1.0f - f0, g1 = 1.0f - f1;
                float* I = img + (size_t)b * XS2;
                corner_atomic(I, r,     c,     amp * g0 * g1);
                corner_atomic(I, r + 1, c,     amp * f0 * g1);
                corner_atomic(I, r + 1, c + 1, amp * f0 * f1);
                corner_atomic(I, r,     c + 1, amp * g0 * f1);
            }
        }
    }
    __syncthreads();

    // reserve bin-contiguous global space per touched bin
    for (int bin = t; bin < NBINS; bin += 256) {
        unsigned cn = lcnt[bin];
        lbase[bin] = cn ? atomicAdd(&gcursor[bin], cn) : 0u;
    }
    __syncthreads();

#pragma unroll
    for (int k = 0; k < K_MAX; k++) {
        unsigned m = meta[k];
        if (m != 0xFFFFFFFFu) {
            unsigned bin = m & (NBINS - 1);
            unsigned idx = lbase[bin] + (m >> 9);
            if (idx < BINCAP) recs[(size_t)bin * BINCAP + idx] = rec[k];
            else rec_fallback(rec[k], (int)bin, img);   // overflow (rare)
        }
    }
}

// ---------------------------------------------------------------------------
// Pass 2: dual-parity 2x2 u64 cells -> exactly ONE ds_add_u64 per record.
// Even tile cell j covers columns (2j, 2j+1); odd tile cell j covers
// (2j+1, (2j+2)&255). Fields: q0=(r0,cLo) q1=(r1,cLo) q2=(r0,cHi) q3=(r1,cHi).
// Reads are bin-contiguous and coalesced (lesson from R7's gather regression).
// ---------------------------------------------------------------------------
__global__ void __launch_bounds__(256)
accum_kernel(const unsigned long long* __restrict__ recs,
             const unsigned* __restrict__ gcursor,
             float* __restrict__ reps,
             float* __restrict__ aprons, int B) {
    int bin = blockIdx.x >> 1, sp = blockIdx.x & 1;   // SPLIT=2
    int b = bin >> 5, g = bin & 31;
    __shared__ unsigned long long teven[BR * CELLW];  // 8 KB
    __shared__ unsigned long long todd[BR * CELLW];   // 8 KB
    int t = threadIdx.x;
    for (int k = t; k < BR * CELLW; k += 256) { teven[k] = 0ull; todd[k] = 0ull; }
    __syncthreads();

    unsigned cnt = min(gcursor[bin], (unsigned)BINCAP);
    unsigned lo = (unsigned)(((unsigned long long)cnt * sp) / SPLIT);
    unsigned hi = (unsigned)(((unsigned long long)cnt * (sp + 1)) / SPLIT);
    const unsigned long long* rb = recs + (size_t)bin * BINCAP;

    for (unsigned i = lo + t; i < hi; i += 256) {
        unsigned long long rc = rb[i];
        unsigned w = (unsigned)rc;
        float amp = __uint_as_float((unsigned)(rc >> 32));
        int rig = w & 7, wc = (w >> 3) & 255;
        float f0 = (float)((w >> 13) & 511) * (1.0f / 512.0f);
        float f1 = (float)((w >> 22) & 511) * (1.0f / 512.0f);
        float g0 = 1.0f - f0, g1 = 1.0f - f1;
        bool cv0 = (w >> 11) & 1, cv1 = (w >> 12) & 1;
        int q00 = cv0 ? __float2int_rn(amp * g0 * g1 * QS) : 0;  // (r,   cLo)
        int q10 = cv0 ? __float2int_rn(amp * f0 * g1 * QS) : 0;  // (r+1, cLo)
        int q01 = cv1 ? __float2int_rn(amp * g0 * f1 * QS) : 0;  // (r,   cHi)
        int q11 = cv1 ? __float2int_rn(amp * f0 * f1 * QS) : 0;  // (r+1, cHi)
        unsigned long long inc = pack4(q00, q10, q01, q11);
        unsigned long long* tile = (wc & 1) ? todd : teven;
        if (inc) lds_add_u64(&tile[rig * CELLW + (wc >> 1)], inc);
    }
    __syncthreads();

    // flush: thread t = column c; carry r1-parts downward; row 8 -> apron.
    int c = t;
    int je = c >> 1;                                       // even tile cell
    int jo = (c & 1) ? (c >> 1) : (((c + 254) & 255) >> 1);// odd tile cell
    bool e_lo = (c & 1) == 0;   // even tile: this column is cLo (fields 0,1)
    bool o_lo = (c & 1) == 1;   // odd tile:  this column is cLo (fields 0,1)
    const float invS = 1.0f / QS;
    float* rep = reps + ((size_t)sp * B + b) * XS2;
    float carry = 0.0f;
#pragma unroll
    for (int rig = 0; rig < BR; rig++) {
        long long se = (long long)teven[rig * CELLW + je];
        int e0 = (int)(short)(se & 0xffff); se = (se - e0) >> 16;
        int e1 = (int)(short)(se & 0xffff); se = (se - e1) >> 16;
        int e2 = (int)(short)(se & 0xffff); se = (se - e2) >> 16;
        int e3 = (int)se;
        long long so = (long long)todd[rig * CELLW + jo];
        int o0 = (int)(short)(so & 0xffff); so = (so - o0) >> 16;
        int o1 = (int)(short)(so & 0xffff); so = (so - o1) >> 16;
        int o2 = (int)(short)(so & 0xffff); so = (so - o2) >> 16;
        int o3 = (int)so;
        float r0 = (e_lo ? (float)e0 : (float)e2) + (o_lo ? (float)o0 : (float)o2);
        float r1 = (e_lo ? (float)e1 : (float)e3) + (o_lo ? (float)o1 : (float)o3);
        rep[(g * BR + rig) * XS + c] = (carry + r0) * invS;
        carry = r1;
    }
    aprons[((size_t)bin * 2 + sp) * XS + c] = carry * invS;
}

// ---------------------------------------------------------------------------
// Fallback direct-scatter (tiny ws / unexpected shapes).
// ---------------------------------------------------------------------------
__global__ void scatter_kernel(const float* __restrict__ flow,
                               const float* __restrict__ values,
                               const int* __restrict__ inds,
                               const float* __restrict__ rot,
                               const float* __restrict__ shifts,
                               float* __restrict__ img, int N) {
    int b = blockIdx.y;
    int n = blockIdx.x * blockDim.x + threadIdx.x;
    if (n >= N) return;
    int r, c; float f0, f1;
    compute_rc(flow, inds, rot, shifts, b, n, N, r, c, f0, f1);
    float amp = values[n];
    float g0 = 1.0f - f0, g1 = 1.0f - f1;
    float* I = img + (size_t)b * XS2;
    corner_atomic(I, r,     c,     amp * g0 * g1);
    corner_atomic(I, r + 1, c,     amp * f0 * g1);
    corner_atomic(I, r + 1, c + 1, amp * f0 * f1);
    corner_atomic(I, r,     c + 1, amp * g0 * f1);
}

// ---------------------------------------------------------------------------
// MLP split-K partials.
// ---------------------------------------------------------------------------
__global__ void mlp_partial(const float* __restrict__ x,
                            const float* __restrict__ w1,
                            float* __restrict__ hraw, int B) {
    int base = blockIdx.x * 256;
    int t = threadIdx.x;
    if (t >= B * LAT) return;
    int b = t / LAT, l = t - b * LAT;
    const float* xb = x + (size_t)b * XS2 + base;
    const float* w  = w1 + (size_t)base * LAT + l;
    float acc = 0.0f;
#pragma unroll 8
    for (int e = 0; e < 256; e++) acc += xb[e] * w[e * LAT];
    fadd_atomic(&hraw[b * LAT + l], acc);
}

// ---------------------------------------------------------------------------
// Fused combine + separable 3x3 blur + per-batch affine.
// S[row] = img + rep0 + rep1 (+ aprons at row = 8k, k>=1).
// ---------------------------------------------------------------------------
__device__ __forceinline__ float S_load(const float* __restrict__ img,
                                        const float* __restrict__ reps,
                                        const float* __restrict__ aprons,
                                        int B, int b, int row, int c, int fast) {
    size_t o = (size_t)b * XS2 + row * XS + c;
    float v = img[o];
    if (fast) {
        v += reps[o] + reps[(size_t)B * XS2 + o];
        if (row > 0 && (row & 7) == 0) {
            size_t bin = (size_t)b * NG + ((row >> 3) - 1);
            v += aprons[bin * 2 * XS + c] + aprons[(bin * 2 + 1) * XS + c];
        }
    }
    return v;
}

__global__ void blur_kernel(const float* __restrict__ img,
                            const float* __restrict__ reps,
                            const float* __restrict__ aprons,
                            const float* __restrict__ hraw,
                            const float* __restrict__ b1,
                            const float* __restrict__ w2,
                            const float* __restrict__ b2,
                            float* __restrict__ out, int B, int fast) {
    int b = blockIdx.y, r = blockIdx.x, c = threadIdx.x;
    float av = b2[0], bv = b2[1];
#pragma unroll
    for (int l = 0; l < LAT; l++) {
        float h = hraw[b * LAT + l] + b1[l];
        h = h > 0.0f ? h : 0.0f;
        av += h * w2[l * 2 + 0];
        bv += h * w2[l * 2 + 1];
    }
    const float g   = 0.6065306597126334f;   // exp(-0.5)
    const float inv = 1.0f / (1.0f + 2.0f * g);
    float up  = (r > 0)      ? S_load(img, reps, aprons, B, b, r - 1, c, fast) : 0.0f;
    float mid =                S_load(img, reps, aprons, B, b, r,     c, fast);
    float dn  = (r < XS - 1) ? S_load(img, reps, aprons, B, b, r + 1, c, fast) : 0.0f;
    float v = (g * (up + dn) + mid) * inv;
    __shared__ float row[XS + 2];
    row[c + 1] = v;
    if (c == 0) { row[0] = 0.0f; row[XS + 1] = 0.0f; }
    __syncthreads();
    float hh = (g * (row[c] + row[c + 2]) + v) * inv;
    out[(size_t)b * XS2 + (size_t)r * XS + c] = av * hh + bv;
}

extern "C" void kernel_launch(void* const* d_in, const int* in_sizes, int n_in,
                              void* d_out, int out_size, void* d_ws, size_t ws_size,
                              hipStream_t stream) {
    const float* flow   = (const float*)d_in[0];
    const float* x      = (const float*)d_in[1];
    const float* values = (const float*)d_in[2];
    const float* rot    = (const float*)d_in[3];
    const float* shifts = (const float*)d_in[4];
    const float* w1     = (const float*)d_in[5];
    const float* b1     = (const float*)d_in[6];
    const float* w2     = (const float*)d_in[7];
    const float* b2     = (const float*)d_in[8];
    const int*   inds   = (const int*)d_in[9];

    int N = in_sizes[2];          // values: (N,)
    int B = in_sizes[4] / 2;      // shifts: (B,2)
    int TI  = B * N;
    int IPB = (TI + P1 - 1) / P1;

    // workspace layout (recs offset 8B-aligned: imgElems*4 + 1024 + 2048)
    size_t imgElems = (size_t)B * XS2;
    float*    img     = (float*)d_ws;
    float*    hraw    = img + imgElems;                   // 256 floats reserved
    unsigned* gcursor = (unsigned*)(hraw + 256);          // NBINS (512)
    unsigned long long* recs = (unsigned long long*)(gcursor + NBINS);  // NBINS*BINCAP
    float*    reps    = (float*)(recs + (size_t)NBINS * BINCAP);        // 2*B*XS2
    float*    aprons  = reps + 2 * imgElems;              // NBINS*2*XS
    size_t needed = (size_t)((char*)(aprons + (size_t)NBINS * 2 * XS) - (char*)d_ws);

    bool fast = (B * NG == NBINS) && (ws_size >= needed) && (IPB <= K_MAX * 256);

    hipMemsetAsync(d_ws, 0, imgElems * sizeof(float) + 1024 + NBINS * 4, stream);

    if (fast) {
        place_kernel<<<P1, 256, 0, stream>>>(flow, values, inds, rot, shifts,
                                             gcursor, recs, img, N, TI, IPB);
        accum_kernel<<<NBINS * SPLIT, 256, 0, stream>>>(recs, gcursor, reps, aprons, B);
    } else {
        dim3 g1((N + 255) / 256, B);
        scatter_kernel<<<g1, 256, 0, stream>>>(flow, values, inds, rot, shifts, img, N);
    }

    mlp_partial<<<XS2 / 256, 256, 0, stream>>>(x, w1, hraw, B);

    dim3 g3(XS, B);
    blur_kernel<<<g3, XS, 0, stream>>>(img, reps, aprons, hraw, b1, w2, b2,
                                       (float*)d_out, B, fast ? 1 : 0);
}

// Round 9
// 216.190 us; speedup vs baseline: 1.3792x; 1.0228x over previous
//
#include <hip/hip_runtime.h>

#define XS     256
#define XS2    65536
#define LAT    10
#define BR     8             // rows per bin group
#define NG     (XS / BR)     // 32 groups per image
#define NBINS  512           // B(16) * NG(32)
#define P1     2048          // blocks for place pass (proven best in R6)
#define MLPB   256           // extra blocks fused onto place for the MLP
#define K_MAX  16            // items per thread in place (IPB<=4096)
#define BINCAP 15360         // per-bin record capacity (mean ~12.4k)
#define SPLIT  2             // accum sub-blocks per bin
#define CELLW  128           // 2x2 cells: 128 column-pairs
#define QS     256.0f        // fixed-point scale 2^8 (field range +-128)

// Native no-return f32 global atomic (global_atomic_add_f32).
__device__ __forceinline__ void fadd_atomic(float* p, float v) {
    unsafeAtomicAdd(p, v);
}

__device__ __forceinline__ void lds_add_u64(unsigned long long* p,
                                            unsigned long long v) {
    __hip_atomic_fetch_add(p, v, __ATOMIC_RELAXED, __HIP_MEMORY_SCOPE_WORKGROUP);
}

// pack 4 signed 16-bit fixed-point fields into a u64 (carry-exact under add
// while every partial field-sum stays within +-2^15).
__device__ __forceinline__ unsigned long long pack4(int q0, int q1, int q2, int q3) {
    return (unsigned long long)((long long)q0 + ((long long)q1 << 16) +
                                ((long long)q2 << 32) + ((long long)q3 << 48));
}

// ---------------------------------------------------------------------------
// Coordinate math (fmaf-pinned; shared by all paths).
// ---------------------------------------------------------------------------
__device__ __forceinline__ void compute_rc(const float* __restrict__ flow,
                                           const int* __restrict__ inds,
                                           const float* __restrict__ rot,
                                           const float* __restrict__ shifts,
                                           int b, int n, int N,
                                           int& r, int& c, float& f0, float& f1) {
    const float* R = rot + b * 9;
    float r00 = R[0], r01 = R[1], r02 = R[2];
    float r10 = R[3], r11 = R[4], r12 = R[5];
    float s0 = shifts[b * 2 + 0], s1 = shifts[b * 2 + 1];
    size_t fo = ((size_t)b * N + n) * 3;
    float fw0 = flow[fo + 0], fw1 = flow[fo + 1], fw2 = flow[fo + 2];
    float v0 = (float)inds[n * 3 + 2] - 128.0f + fw0;
    float v1 = (float)inds[n * 3 + 1] - 128.0f + fw1;
    float v2 = (float)inds[n * 3 + 0] - 128.0f + fw2;
    float p0 = fmaf(v0, r00, fmaf(v1, r01, fmaf(v2, r02, 128.0f - s0)));
    float p1 = fmaf(v0, r10, fmaf(v1, r11, fmaf(v2, r12, 128.0f - s1)));
    float cs0 = p1, cs1 = p0;     // c_sampling = (coords[...,1], coords[...,0])
    float ff0 = floorf(cs0), ff1 = floorf(cs1);
    r = (int)ff0; c = (int)ff1;
    f0 = cs0 - ff0; f1 = cs1 - ff1;
}

// JAX .at[].add semantics: negative indices wrap once, then OOB dropped.
__device__ __forceinline__ void corner_atomic(float* I, int rr, int cc, float a) {
    if (rr >= -XS && rr < XS && cc >= -XS && cc < XS)
        fadd_atomic(I + ((rr + XS) & (XS - 1)) * XS + ((cc + XS) & (XS - 1)), a);
}

// fast path iff rows r, r+1 both valid and don't wrap-split.
__device__ __forceinline__ bool is_fast(int r) {
    return (r >= -XS) && (r <= XS - 2) && (r != -1);
}

// Record: low = rig[0:2] wc[3:10] cv0[11] cv1[12] q0[13:21] q1[22:30];
// high = amp f32 bits.
__device__ __forceinline__ void rec_fallback(unsigned long long rec, int bin,
                                             float* __restrict__ img) {
    unsigned w = (unsigned)rec;
    float amp = __uint_as_float((unsigned)(rec >> 32));
    int b = bin >> 5, g = bin & 31;
    int rig = w & 7, wc = (w >> 3) & 255;
    int wr = g * BR + rig;
    float f0 = (float)((w >> 13) & 511) * (1.0f / 512.0f);
    float f1 = (float)((w >> 22) & 511) * (1.0f / 512.0f);
    float g0 = 1.0f - f0, g1 = 1.0f - f1;
    float* I = img + (size_t)b * XS2;
    if (w & (1u << 11)) {
        fadd_atomic(&I[wr * XS + wc],       amp * g0 * g1);
        fadd_atomic(&I[(wr + 1) * XS + wc], amp * f0 * g1);
    }
    if (w & (1u << 12)) {
        int wc1 = (wc + 1) & 255;
        fadd_atomic(&I[wr * XS + wc1],       amp * g0 * f1);
        fadd_atomic(&I[(wr + 1) * XS + wc1], amp * f0 * f1);
    }
}

// ---------------------------------------------------------------------------
// Pass 1 (fused hist+place+MLP): blocks [0,P1) do the scatter binning;
// blocks [P1, P1+MLPB) compute the split-K MLP partials (independent work
// fused to save a dispatch and hide under place's runtime).
// ---------------------------------------------------------------------------
__global__ void __launch_bounds__(256)
place_kernel(const float* __restrict__ flow,
             const float* __restrict__ values,
             const int* __restrict__ inds,
             const float* __restrict__ rot,
             const float* __restrict__ shifts,
             const float* __restrict__ x,
             const float* __restrict__ w1,
             float* __restrict__ hraw,
             unsigned* __restrict__ gcursor,
             unsigned long long* __restrict__ recs,
             float* __restrict__ img,
             int N, int TI, int IPB, int B) {
    int t = threadIdx.x;

    if (blockIdx.x >= P1) {                 // ---- fused MLP path ----
        int base = (blockIdx.x - P1) * 256;
        if (t < B * LAT) {
            int b = t / LAT, l = t - b * LAT;
            const float* xb = x + (size_t)b * XS2 + base;
            const float* w  = w1 + (size_t)base * LAT + l;
            float acc = 0.0f;
#pragma unroll 8
            for (int e = 0; e < 256; e++) acc += xb[e] * w[e * LAT];
            fadd_atomic(&hraw[b * LAT + l], acc);
        }
        return;
    }

    __shared__ unsigned lcnt[NBINS];
    __shared__ unsigned lbase[NBINS];
    lcnt[t] = 0; lcnt[t + 256] = 0;
    __syncthreads();

    unsigned long long rec[K_MAX];
    unsigned meta[K_MAX];        // bin | rank<<9 ; 0xFFFFFFFF = none
    int s = blockIdx.x * IPB;
    int e = min(s + IPB, TI);

#pragma unroll
    for (int k = 0; k < K_MAX; k++) {
        meta[k] = 0xFFFFFFFFu;
        int i = s + t + k * 256;
        if (i < e) {
            int b = i / N, n = i - b * N;
            int r, c; float f0, f1;
            compute_rc(flow, inds, rot, shifts, b, n, N, r, c, f0, f1);
            float amp = values[n];
            if (is_fast(r)) {
                int wr = (r + XS) & (XS - 1);
                int wc = c & (XS - 1);
                unsigned cv0 = (c >= -XS && c < XS) ? 1u : 0u;
                unsigned cv1 = (c + 1 >= -XS && c + 1 < XS) ? 1u : 0u;
                unsigned q0 = min(511u, (unsigned)(f0 * 512.0f + 0.5f));
                unsigned q1 = min(511u, (unsigned)(f1 * 512.0f + 0.5f));
                unsigned word = (unsigned)(wr & 7) | ((unsigned)wc << 3) |
                                (cv0 << 11) | (cv1 << 12) | (q0 << 13) | (q1 << 22);
                int bin = b * NG + (wr >> 3);
                unsigned rank = atomicAdd(&lcnt[bin], 1u);
                meta[k] = (unsigned)bin | (rank << 9);   // rank < 4096 < 2^13
                rec[k] = ((unsigned long long)__float_as_uint(amp) << 32) | word;
            } else {
                float g0 = 1.0f - f0, g1 = 1.0f - f1;
                float* I = img + (size_t)b * XS2;
                corner_atomic(I, r,     c,     amp * g0 * g1);
                corner_atomic(I, r + 1, c,     amp * f0 * g1);
                corner_atomic(I, r + 1, c + 1, amp * f0 * f1);
                corner_atomic(I, r,     c + 1, amp * g0 * f1);
            }
        }
    }
    __syncthreads();

    // reserve bin-contiguous global space per touched bin
    for (int bin = t; bin < NBINS; bin += 256) {
        unsigned cn = lcnt[bin];
        lbase[bin] = cn ? atomicAdd(&gcursor[bin], cn) : 0u;
    }
    __syncthreads();

#pragma unroll
    for (int k = 0; k < K_MAX; k++) {
        unsigned m = meta[k];
        if (m != 0xFFFFFFFFu) {
            unsigned bin = m & (NBINS - 1);
            unsigned idx = lbase[bin] + (m >> 9);
            if (idx < BINCAP) recs[(size_t)bin * BINCAP + idx] = rec[k];
            else rec_fallback(rec[k], (int)bin, img);   // overflow (rare)
        }
    }
}

// ---------------------------------------------------------------------------
// Pass 2: dual-parity 2x2 u64 cells -> exactly ONE ds_add_u64 per record.
// Even tile cell j covers columns (2j, 2j+1); odd tile cell j covers
// (2j+1, (2j+2)&255). Fields: q0=(r0,cLo) q1=(r1,cLo) q2=(r0,cHi) q3=(r1,cHi).
// Reads are bin-contiguous and coalesced.
// ---------------------------------------------------------------------------
__global__ void __launch_bounds__(256)
accum_kernel(const unsigned long long* __restrict__ recs,
             const unsigned* __restrict__ gcursor,
             float* __restrict__ reps,
             float* __restrict__ aprons, int B) {
    int bin = blockIdx.x >> 1, sp = blockIdx.x & 1;   // SPLIT=2
    int b = bin >> 5, g = bin & 31;
    __shared__ unsigned long long teven[BR * CELLW];  // 8 KB
    __shared__ unsigned long long todd[BR * CELLW];   // 8 KB
    int t = threadIdx.x;
    for (int k = t; k < BR * CELLW; k += 256) { teven[k] = 0ull; todd[k] = 0ull; }
    __syncthreads();

    unsigned cnt = min(gcursor[bin], (unsigned)BINCAP);
    unsigned lo = (unsigned)(((unsigned long long)cnt * sp) / SPLIT);
    unsigned hi = (unsigned)(((unsigned long long)cnt * (sp + 1)) / SPLIT);
    const unsigned long long* rb = recs + (size_t)bin * BINCAP;

    for (unsigned i = lo + t; i < hi; i += 256) {
        unsigned long long rc = rb[i];
        unsigned w = (unsigned)rc;
        float amp = __uint_as_float((unsigned)(rc >> 32));
        int rig = w & 7, wc = (w >> 3) & 255;
        float f0 = (float)((w >> 13) & 511) * (1.0f / 512.0f);
        float f1 = (float)((w >> 22) & 511) * (1.0f / 512.0f);
        float g0 = 1.0f - f0, g1 = 1.0f - f1;
        bool cv0 = (w >> 11) & 1, cv1 = (w >> 12) & 1;
        int q00 = cv0 ? __float2int_rn(amp * g0 * g1 * QS) : 0;  // (r,   cLo)
        int q10 = cv0 ? __float2int_rn(amp * f0 * g1 * QS) : 0;  // (r+1, cLo)
        int q01 = cv1 ? __float2int_rn(amp * g0 * f1 * QS) : 0;  // (r,   cHi)
        int q11 = cv1 ? __float2int_rn(amp * f0 * f1 * QS) : 0;  // (r+1, cHi)
        unsigned long long inc = pack4(q00, q10, q01, q11);
        unsigned long long* tile = (wc & 1) ? todd : teven;
        lds_add_u64(&tile[rig * CELLW + (wc >> 1)], inc);
    }
    __syncthreads();

    // flush: thread t = column c; carry r1-parts downward; row 8 -> apron.
    int c = t;
    int je = c >> 1;                                       // even tile cell
    int jo = (c & 1) ? (c >> 1) : (((c + 254) & 255) >> 1);// odd tile cell
    bool e_lo = (c & 1) == 0;   // even tile: this column is cLo (fields 0,1)
    bool o_lo = (c & 1) == 1;   // odd tile:  this column is cLo (fields 0,1)
    const float invS = 1.0f / QS;
    float* rep = reps + ((size_t)sp * B + b) * XS2;
    float carry = 0.0f;
#pragma unroll
    for (int rig = 0; rig < BR; rig++) {
        long long se = (long long)teven[rig * CELLW + je];
        int e0 = (int)(short)(se & 0xffff); se = (se - e0) >> 16;
        int e1 = (int)(short)(se & 0xffff); se = (se - e1) >> 16;
        int e2 = (int)(short)(se & 0xffff); se = (se - e2) >> 16;
        int e3 = (int)se;
        long long so = (long long)todd[rig * CELLW + jo];
        int o0 = (int)(short)(so & 0xffff); so = (so - o0) >> 16;
        int o1 = (int)(short)(so & 0xffff); so = (so - o1) >> 16;
        int o2 = (int)(short)(so & 0xffff); so = (so - o2) >> 16;
        int o3 = (int)so;
        float r0 = (e_lo ? (float)e0 : (float)e2) + (o_lo ? (float)o0 : (float)o2);
        float r1 = (e_lo ? (float)e1 : (float)e3) + (o_lo ? (float)o1 : (float)o3);
        rep[(g * BR + rig) * XS + c] = (carry + r0) * invS;
        carry = r1;
    }
    aprons[((size_t)bin * 2 + sp) * XS + c] = carry * invS;
}

// ---------------------------------------------------------------------------
// Fallback direct-scatter (tiny ws / unexpected shapes).
// ---------------------------------------------------------------------------
__global__ void scatter_kernel(const float* __restrict__ flow,
                               const float* __restrict__ values,
                               const int* __restrict__ inds,
                               const float* __restrict__ rot,
                               const float* __restrict__ shifts,
                               float* __restrict__ img, int N) {
    int b = blockIdx.y;
    int n = blockIdx.x * blockDim.x + threadIdx.x;
    if (n >= N) return;
    int r, c; float f0, f1;
    compute_rc(flow, inds, rot, shifts, b, n, N, r, c, f0, f1);
    float amp = values[n];
    float g0 = 1.0f - f0, g1 = 1.0f - f1;
    float* I = img + (size_t)b * XS2;
    corner_atomic(I, r,     c,     amp * g0 * g1);
    corner_atomic(I, r + 1, c,     amp * f0 * g1);
    corner_atomic(I, r + 1, c + 1, amp * f0 * f1);
    corner_atomic(I, r,     c + 1, amp * g0 * f1);
}

// ---------------------------------------------------------------------------
// MLP split-K partials (fallback path only; fast path fuses into place).
// ---------------------------------------------------------------------------
__global__ void mlp_partial(const float* __restrict__ x,
                            const float* __restrict__ w1,
                            float* __restrict__ hraw, int B) {
    int base = blockIdx.x * 256;
    int t = threadIdx.x;
    if (t >= B * LAT) return;
    int b = t / LAT, l = t - b * LAT;
    const float* xb = x + (size_t)b * XS2 + base;
    const float* w  = w1 + (size_t)base * LAT + l;
    float acc = 0.0f;
#pragma unroll 8
    for (int e = 0; e < 256; e++) acc += xb[e] * w[e * LAT];
    fadd_atomic(&hraw[b * LAT + l], acc);
}

// ---------------------------------------------------------------------------
// Fused combine + separable 3x3 blur + per-batch affine.
// S[row] = img + rep0 + rep1 (+ aprons at row = 8k, k>=1).
// ---------------------------------------------------------------------------
__device__ __forceinline__ float S_load(const float* __restrict__ img,
                                        const float* __restrict__ reps,
                                        const float* __restrict__ aprons,
                                        int B, int b, int row, int c, int fast) {
    size_t o = (size_t)b * XS2 + row * XS + c;
    float v = img[o];
    if (fast) {
        v += reps[o] + reps[(size_t)B * XS2 + o];
        if (row > 0 && (row & 7) == 0) {
            size_t bin = (size_t)b * NG + ((row >> 3) - 1);
            v += aprons[bin * 2 * XS + c] + aprons[(bin * 2 + 1) * XS + c];
        }
    }
    return v;
}

__global__ void blur_kernel(const float* __restrict__ img,
                            const float* __restrict__ reps,
                            const float* __restrict__ aprons,
                            const float* __restrict__ hraw,
                            const float* __restrict__ b1,
                            const float* __restrict__ w2,
                            const float* __restrict__ b2,
                            float* __restrict__ out, int B, int fast) {
    int b = blockIdx.y, r = blockIdx.x, c = threadIdx.x;
    float av = b2[0], bv = b2[1];
#pragma unroll
    for (int l = 0; l < LAT; l++) {
        float h = hraw[b * LAT + l] + b1[l];
        h = h > 0.0f ? h : 0.0f;
        av += h * w2[l * 2 + 0];
        bv += h * w2[l * 2 + 1];
    }
    const float g   = 0.6065306597126334f;   // exp(-0.5)
    const float inv = 1.0f / (1.0f + 2.0f * g);
    float up  = (r > 0)      ? S_load(img, reps, aprons, B, b, r - 1, c, fast) : 0.0f;
    float mid =                S_load(img, reps, aprons, B, b, r,     c, fast);
    float dn  = (r < XS - 1) ? S_load(img, reps, aprons, B, b, r + 1, c, fast) : 0.0f;
    float v = (g * (up + dn) + mid) * inv;
    __shared__ float row[XS + 2];
    row[c + 1] = v;
    if (c == 0) { row[0] = 0.0f; row[XS + 1] = 0.0f; }
    __syncthreads();
    float hh = (g * (row[c] + row[c + 2]) + v) * inv;
    out[(size_t)b * XS2 + (size_t)r * XS + c] = av * hh + bv;
}

extern "C" void kernel_launch(void* const* d_in, const int* in_sizes, int n_in,
                              void* d_out, int out_size, void* d_ws, size_t ws_size,
                              hipStream_t stream) {
    const float* flow   = (const float*)d_in[0];
    const float* x      = (const float*)d_in[1];
    const float* values = (const float*)d_in[2];
    const float* rot    = (const float*)d_in[3];
    const float* shifts = (const float*)d_in[4];
    const float* w1     = (const float*)d_in[5];
    const float* b1     = (const float*)d_in[6];
    const float* w2     = (const float*)d_in[7];
    const float* b2     = (const float*)d_in[8];
    const int*   inds   = (const int*)d_in[9];

    int N = in_sizes[2];          // values: (N,)
    int B = in_sizes[4] / 2;      // shifts: (B,2)
    int TI  = B * N;
    int IPB = (TI + P1 - 1) / P1;

    // workspace layout (recs offset 8B-aligned: imgElems*4 + 1024 + 2048)
    size_t imgElems = (size_t)B * XS2;
    float*    img     = (float*)d_ws;
    float*    hraw    = img + imgElems;                   // 256 floats reserved
    unsigned* gcursor = (unsigned*)(hraw + 256);          // NBINS (512)
    unsigned long long* recs = (unsigned long long*)(gcursor + NBINS);  // NBINS*BINCAP
    float*    reps    = (float*)(recs + (size_t)NBINS * BINCAP);        // 2*B*XS2
    float*    aprons  = reps + 2 * imgElems;              // NBINS*2*XS
    size_t needed = (size_t)((char*)(aprons + (size_t)NBINS * 2 * XS) - (char*)d_ws);

    bool fast = (B * NG == NBINS) && (ws_size >= needed) && (IPB <= K_MAX * 256);

    hipMemsetAsync(d_ws, 0, imgElems * sizeof(float) + 1024 + NBINS * 4, stream);

    if (fast) {
        place_kernel<<<P1 + MLPB, 256, 0, stream>>>(flow, values, inds, rot, shifts,
                                                    x, w1, hraw, gcursor, recs, img,
                                                    N, TI, IPB, B);
        accum_kernel<<<NBINS * SPLIT, 256, 0, stream>>>(recs, gcursor, reps, aprons, B);
    } else {
        dim3 g1((N + 255) / 256, B);
        scatter_kernel<<<g1, 256, 0, stream>>>(flow, values, inds, rot, shifts, img, N);
        mlp_partial<<<XS2 / 256, 256, 0, stream>>>(x, w1, hraw, B);
    }

    dim3 g3(XS, B);
    blur_kernel<<<g3, XS, 0, stream>>>(img, reps, aprons, hraw, b1, w2, b2,
                                       (float*)d_out, B, fast ? 1 : 0);
}